// Round 9
// baseline (301.429 us; speedup 1.0000x reference)
//
#include <hip/hip_runtime.h>
#include <cstdint>
#include <cstddef>

// CoaT factorized attention block, MI355X/gfx950.
// R14: GEMM K-loop moved to the untested {depth x occupancy} corner:
// BK=32 TRIPLE buffer (72 KB -> 2 blk/CU), 2-ahead prefetch with counted
// vmcnt(3) (tile t+2's 3 loads stay in flight across the barrier; each
// tile's loads get ~2 steps to land vs 1 in R8). Raw s_barrier +
// sched_barrier(0) fences; everything else byte-identical to R8's GEMM.
// kv (R13), conv (R9), combine (R9) frozen.

typedef unsigned short u16;

#define HEADS 8
#define CHD   64
#define CDIM  512
#define NTOK  785
#define BATCH 32
#define MROWS (BATCH * NTOK)   // 25120
#define MPAD  25344            // 99 * 256
#define QKVN  1536
#define IMGHW 784

typedef float  f32x4  __attribute__((ext_vector_type(4)));
typedef __bf16 bf16x8 __attribute__((ext_vector_type(8)));

__device__ __forceinline__ u16 f2bf(float f) {
  union { float f; uint32_t u; } x; x.f = f;
  uint32_t r = x.u + 0x7fffu + ((x.u >> 16) & 1u);  // RNE
  return (u16)(r >> 16);
}
__device__ __forceinline__ float bf2f(u16 u) {
  union { uint32_t u; float f; } x; x.u = ((uint32_t)u) << 16;
  return x.f;
}
__device__ __forceinline__ float bflo(uint32_t u) { return bf2f((u16)(u & 0xffffu)); }
__device__ __forceinline__ float bfhi(uint32_t u) { return bf2f((u16)(u >> 16)); }
// packed f32x2 -> bf16x2 (low = a, high = b)
__device__ __forceinline__ uint32_t pk2(float a, float b) {
#if __has_builtin(__builtin_amdgcn_cvt_pk_bf16_f32)
  auto v = __builtin_amdgcn_cvt_pk_bf16_f32(a, b);
  union { decltype(v) v2; uint32_t u; } cv; cv.v2 = v; return cv.u;
#else
  return (uint32_t)f2bf(a) | ((uint32_t)f2bf(b) << 16);
#endif
}

// ---------------- merged f32 -> bf16 casts (x, qkv_w, proj_w) --------------
__global__ __launch_bounds__(256)
void casts_kernel(const float* __restrict__ x, u16* __restrict__ xb,
                  const float* __restrict__ w1, u16* __restrict__ w1b,
                  const float* __restrict__ w2, u16* __restrict__ w2b) {
  const int N1 = MROWS * CDIM / 4, N2 = QKVN * CDIM / 4, N3 = CDIM * CDIM / 4;
  int i = blockIdx.x * 256 + threadIdx.x;
  const float* src; u16* dst;
  if (i < N1)           { src = x;  dst = xb;  }
  else if (i < N1 + N2) { i -= N1;  src = w1; dst = w1b; }
  else if (i < N1 + N2 + N3) { i -= N1 + N2; src = w2; dst = w2b; }
  else return;
  float4 v = reinterpret_cast<const float4*>(src)[i];
  uint2 o; o.x = pk2(v.x, v.y); o.y = pk2(v.z, v.w);
  reinterpret_cast<uint2*>(dst)[i] = o;
}

// ---------------- async global->LDS, 16B per lane --------------------------
__device__ __forceinline__ void gld_lds16(const u16* g, u16* l) {
  __builtin_amdgcn_global_load_lds((__attribute__((address_space(1))) void*)g,
                                   (__attribute__((address_space(3))) void*)l,
                                   16, 0, 0);
}

// ---------------- bf16 MFMA GEMM, C = A @ W^T + bias -----------------------
// 256x128 tile, 512 threads = 8 waves in 4(row)x2(col); per wave 4x4 of
// 16x16x32 MFMA, one K-chunk of 32 per tile. BK=32 TRIPLE-buffered (72 KB,
// 2 blk/CU), 2-ahead prefetch, counted vmcnt:
//   prologue: stage(0->b0); stage(1->b1); vmcnt(3) [t0 landed]; barrier
//   iter t:   stage(t+2 -> b[(t+2)%3]); ds_read b[t%3]; 16 MFMA;
//             vmcnt(3 if t+2 staged else 0) [t+1 landed, t+2 in flight];
//             s_barrier
// Buffer-reuse race audit: b[(t+2)%3] written at step t was last read at
// step t-1; all readers crossed the step-(t-1) barrier with ds_reads
// drained (compiler lgkmcnt precedes the MFMAs before that barrier).
// Swizzle / staging indices identical to R8.
template <int OUTBF16>
__global__ __launch_bounds__(512)
void gemm_bt(const u16* __restrict__ A, const u16* __restrict__ W,
             const float* __restrict__ bias, void* __restrict__ Cout,
             int Mstore, int N, int K, int nMt, int nNt) {
  __shared__ __align__(16) u16 lsA[3][256 * 32];   // 48 KB
  __shared__ __align__(16) u16 lsB[3][128 * 32];   // 24 KB
  const int flat = blockIdx.x;
  const int xcd = flat & 7, idx = flat >> 3;
  const int nt = idx % nNt;
  const int mt = (idx / nNt) * 8 + xcd;
  if (mt >= nMt) return;
  const int tile_m = mt * 256, tile_n = nt * 128;

  const int tid  = threadIdx.x;
  const int wave = tid >> 6, lane = tid & 63;
  const int quad = lane >> 4, l16 = lane & 15;
  const int wm = (wave & 3) * 64, wn = (wave >> 2) * 64;

  const int srow = tid >> 2;                               // 0..127
  const int scol = ((tid & 3) ^ ((tid >> 3) & 3)) * 8;
  const int ldst = tid * 8;

  auto stage = [&](int kt, int buf) {
    const int kc = kt * 32 + scol;
#pragma unroll
    for (int s = 0; s < 2; ++s)
      gld_lds16(A + (size_t)(tile_m + s * 128 + srow) * K + kc,
                &lsA[buf][s * 4096 + ldst]);
    gld_lds16(W + (size_t)(tile_n + srow) * K + kc, &lsB[buf][ldst]);
  };

  f32x4 acc[4][4] = {};

  // prologue: tiles 0 and 1 in flight; wait tile 0 (3 of 6 remain)
  stage(0, 0);
  stage(1, 1);
  asm volatile("s_waitcnt vmcnt(3)" ::: "memory");
  __builtin_amdgcn_sched_barrier(0);
  __builtin_amdgcn_s_barrier();
  __builtin_amdgcn_sched_barrier(0);

  const int KT = K >> 5;                 // 16 at both call sites
  const int pch = (quad ^ ((l16 >> 1) & 3)) * 8;   // physical chunk offset
  int cur = 0, nx2 = 2;                  // buf of tile t, buf of tile t+2
  for (int t = 0; t < KT; ++t) {
    // issue tile t+2 into the buffer freed at the end of step t-1
    if (t + 2 < KT) stage(t + 2, nx2);
    bf16x8 af[4], bfr[4];
#pragma unroll
    for (int i = 0; i < 4; ++i) {
      af[i]  = *reinterpret_cast<const bf16x8*>(
          &lsA[cur][(wm + i * 16 + l16) * 32 + pch]);
      bfr[i] = *reinterpret_cast<const bf16x8*>(
          &lsB[cur][(wn + i * 16 + l16) * 32 + pch]);
    }
#pragma unroll
    for (int i = 0; i < 4; ++i)
#pragma unroll
      for (int j = 0; j < 4; ++j)
        acc[i][j] = __builtin_amdgcn_mfma_f32_16x16x32_bf16(
            af[i], bfr[j], acc[i][j], 0, 0, 0);
    // end of step: tile t+1 must be resident for the next iteration;
    // tile t+2's 3 loads stay in flight across the barrier (never 0 mid-loop)
    if (t + 1 < KT) {
      if (t + 2 < KT) asm volatile("s_waitcnt vmcnt(3)" ::: "memory");
      else            asm volatile("s_waitcnt vmcnt(0)" ::: "memory");
      __builtin_amdgcn_sched_barrier(0);
      __builtin_amdgcn_s_barrier();
      __builtin_amdgcn_sched_barrier(0);
    }
    cur = (cur == 2) ? 0 : cur + 1;
    nx2 = (nx2 == 2) ? 0 : nx2 + 1;
  }

  // C/D layout: col = lane&15, row = quad*4 + reg
#pragma unroll
  for (int i = 0; i < 4; ++i) {
    const int mbase = tile_m + wm + i * 16 + quad * 4;
#pragma unroll
    for (int j = 0; j < 4; ++j) {
      const int n  = tile_n + wn + j * 16 + l16;
      const float bv = bias[n];
      const float v0 = acc[i][j][0] + bv, v1 = acc[i][j][1] + bv;
      const float v2 = acc[i][j][2] + bv, v3 = acc[i][j][3] + bv;
      if (OUTBF16) {
        u16* cp = reinterpret_cast<u16*>(Cout) + (size_t)mbase * N + n;
        const uint32_t p01 = pk2(v0, v1), p23 = pk2(v2, v3);
        if (mbase + 0 < Mstore) cp[0]            = (u16)p01;
        if (mbase + 1 < Mstore) cp[(size_t)N]    = (u16)(p01 >> 16);
        if (mbase + 2 < Mstore) cp[(size_t)N*2]  = (u16)p23;
        if (mbase + 3 < Mstore) cp[(size_t)N*3]  = (u16)(p23 >> 16);
      } else {
        float* cp = reinterpret_cast<float*>(Cout) + (size_t)mbase * N + n;
        if (mbase + 0 < Mstore) cp[0]           = v0;
        if (mbase + 1 < Mstore) cp[(size_t)N]   = v1;
        if (mbase + 2 < Mstore) cp[(size_t)N*2] = v2;
        if (mbase + 3 < Mstore) cp[(size_t)N*3] = v3;
      }
    }
  }
}

// ---------------- kv: full-token pass, pipelined, writes kvT directly ------
// Thread t owns c = (t&15)*4+{0..3}, d = (t>>4)*4+{0..3}; stages rows
// nl0 = t>>4 and nl0+16 of each 32-token chunk (4 uint2 loads -> regs).
// Double-buffered LDS, 1 barrier/chunk.
__device__ __forceinline__ void kv_part(
    const u16* __restrict__ qkv, u16* __restrict__ kvT, int bh,
    float* __restrict__ e_s, float* __restrict__ v_s) {
  const int b = bh >> 3, h = bh & 7;
  const int t = threadIdx.x;
  const int c4 = (t & 15) * 4;
  const int d4 = (t >> 4) * 4;
  const int nl0 = t >> 4;                 // 0..15
  const u16* kbase = qkv + (size_t)(b * NTOK) * QKVN + CDIM + h * CHD;
  const u16* vbase = kbase + CDIM;
  f32x4 acc[4] = {};              // acc[ci]: c = c4+ci, d = d4+{0..3}
  f32x4 sp4 = {0.f, 0.f, 0.f, 0.f};

  const int NCH = (NTOK + 31) / 32;       // 25
  uint2 rk0, rv0, rk1, rv1;
  auto issue = [&](int c) {
    const int na = c * 32 + nl0, nb = na + 16;
    if (na < NTOK) {
      rk0 = *reinterpret_cast<const uint2*>(&kbase[(size_t)na * QKVN + c4]);
      rv0 = *reinterpret_cast<const uint2*>(&vbase[(size_t)na * QKVN + c4]);
    }
    if (nb < NTOK) {
      rk1 = *reinterpret_cast<const uint2*>(&kbase[(size_t)nb * QKVN + c4]);
      rv1 = *reinterpret_cast<const uint2*>(&vbase[(size_t)nb * QKVN + c4]);
    }
  };

  issue(0);
  for (int c = 0; c < NCH; ++c) {
    float* eb = e_s + (c & 1) * 2048;
    float* vb = v_s + (c & 1) * 2048;
    const int na = c * 32 + nl0, nb = na + 16;
    f32x4 e4a = {}, v4a = {}, e4b = {}, v4b = {};
    if (na < NTOK) {
      e4a[0] = __expf(bflo(rk0.x)); e4a[1] = __expf(bfhi(rk0.x));
      e4a[2] = __expf(bflo(rk0.y)); e4a[3] = __expf(bfhi(rk0.y));
      v4a[0] = bflo(rv0.x); v4a[1] = bfhi(rv0.x);
      v4a[2] = bflo(rv0.y); v4a[3] = bfhi(rv0.y);
    }
    if (nb < NTOK) {
      e4b[0] = __expf(bflo(rk1.x)); e4b[1] = __expf(bfhi(rk1.x));
      e4b[2] = __expf(bflo(rk1.y)); e4b[3] = __expf(bfhi(rk1.y));
      v4b[0] = bflo(rv1.x); v4b[1] = bfhi(rv1.x);
      v4b[2] = bflo(rv1.y); v4b[3] = bfhi(rv1.y);
    }
    *reinterpret_cast<f32x4*>(&eb[nl0 * 64 + c4]) = e4a;
    *reinterpret_cast<f32x4*>(&vb[nl0 * 64 + c4]) = v4a;
    *reinterpret_cast<f32x4*>(&eb[(nl0 + 16) * 64 + c4]) = e4b;
    *reinterpret_cast<f32x4*>(&vb[(nl0 + 16) * 64 + c4]) = v4b;
    sp4 += e4a + e4b;
    if (c + 1 < NCH) issue(c + 1);    // next chunk's loads fly under compute
    __syncthreads();
    const int nc = min(32, NTOK - c * 32);
    for (int nl = 0; nl < nc; ++nl) {
      const f32x4 e4 = *reinterpret_cast<const f32x4*>(&eb[nl * 64 + c4]);
      const f32x4 v4 = *reinterpret_cast<const f32x4*>(&vb[nl * 64 + d4]);
      acc[0] += e4[0] * v4;
      acc[1] += e4[1] * v4;
      acc[2] += e4[2] * v4;
      acc[3] += e4[3] * v4;
    }
  }
  // S-reduction: S[c] = sum over the 16 threads with (t&15)==c>>2 of sp4[c&3]
  __syncthreads();
  *reinterpret_cast<f32x4*>(&e_s[t * 4]) = sp4;
  __syncthreads();
  if (t < 64) {
    float S = 0.f;
#pragma unroll
    for (int m = 0; m < 16; ++m)
      S += e_s[((t >> 2) + 16 * m) * 4 + (t & 3)];
    v_s[t] = S;
  }
  __syncthreads();
  const float S0 = v_s[c4], S1 = v_s[c4 + 1], S2 = v_s[c4 + 2], S3 = v_s[c4 + 3];
  // kvT[bh][d][c] = acc/S, bf16; per di a uint2 (4 c values) coalesced store
  u16* kb = kvT + (size_t)bh * 4096 + (size_t)d4 * 64 + c4;
#pragma unroll
  for (int di = 0; di < 4; ++di) {
    uint2 o;
    o.x = pk2(acc[0][di] / S0, acc[1][di] / S1);
    o.y = pk2(acc[2][di] / S2, acc[3][di] / S3);
    *reinterpret_cast<uint2*>(&kb[(size_t)di * 64]) = o;
  }
}

// ---------------- depthwise conv + EV fuse ---------------------------------
template <int KS>
__device__ __forceinline__ void conv_head(
    const u16* __restrict__ qkv, const float* __restrict__ wgt,
    const float* __restrict__ bias, int b, int head, int hh, int yt,
    u16* __restrict__ evbuf, u16* __restrict__ ls, float* __restrict__ wls) {
  constexpr int PAD = KS / 2;
  constexpr int RIN = 4 + 2 * PAD;
  const int t = threadIdx.x;
  const int y0 = yt * 4;
  const u16* vimg = qkv + (size_t)(b * NTOK + 1) * QKVN + 2 * CDIM + head * 64;
  // stage weights for this head group, coalesced
  for (int i = t; i < 64 * KS * KS; i += 256)
    wls[i] = wgt[hh * 64 * KS * KS + i];
  const int c8 = (t & 7) * 8;
  for (int pi = t >> 3; pi < RIN * 28; pi += 32) {
    const int ry = pi / 28, rx = pi - ry * 28;
    const int yy = y0 - PAD + ry;
    uint4 val = {0, 0, 0, 0};
    if (yy >= 0 && yy < 28)
      val = *reinterpret_cast<const uint4*>(vimg + (size_t)(yy * 28 + rx) * QKVN + c8);
    *reinterpret_cast<uint4*>(ls + pi * 64 + c8) = val;
  }
  __syncthreads();
  const int d = t & 63, yl = t >> 6;
  float wr[KS * KS];
#pragma unroll
  for (int i = 0; i < KS * KS; ++i) wr[i] = wls[d * KS * KS + i];
  const float bv = bias[hh * 64 + d];
  float acc[28];
#pragma unroll
  for (int x = 0; x < 28; ++x) acc[x] = bv;
#pragma unroll
  for (int xx = 0; xx < 28; ++xx) {
    float col[KS];
#pragma unroll
    for (int r = 0; r < KS; ++r)
      col[r] = bf2f(ls[((yl + r) * 28 + xx) * 64 + d]);
#pragma unroll
    for (int j = 0; j < KS; ++j) {
      const int x = xx + PAD - j;
      if (x >= 0 && x < 28) {
#pragma unroll
        for (int r = 0; r < KS; ++r)
          acc[x] += col[r] * wr[r * KS + j];
      }
    }
  }
  const int p0 = (y0 + yl) * 28;
  const u16* qrow = qkv + (size_t)(b * NTOK + 1 + p0) * QKVN + head * 64 + d;
  u16* obase = evbuf + (((size_t)(b * 8 + head)) * IMGHW + p0) * 64 + d;
#pragma unroll
  for (int x = 0; x < 28; ++x) {
    const float ev = acc[x] * bf2f(qrow[(size_t)x * QKVN]);
    obase[(size_t)x * 64] = f2bf(ev);
  }
}

// ---------------- merged kv + conv (independent work, one launch) ----------
// grid (256, 8): y == 0 -> kv (full token range); y >= 1 -> conv yt = y-1.
__global__ __launch_bounds__(256)
void kv_conv_kernel(const u16* __restrict__ qkv, u16* __restrict__ kvT,
                    const float* __restrict__ w3, const float* __restrict__ b3,
                    const float* __restrict__ w5, const float* __restrict__ b5,
                    const float* __restrict__ w7, const float* __restrict__ b7,
                    u16* __restrict__ evbuf) {
  __shared__ __align__(16) char smem[10 * 28 * 64 * 2 + 64 * 49 * 4];  // 48.4 KB
  const int y = blockIdx.y;
  if (y == 0) {
    float* e_s = reinterpret_cast<float*>(smem);            // 2 x 8 KB
    float* v_s = e_s + 2 * 2048;                            // 2 x 8 KB
    kv_part(qkv, kvT, blockIdx.x, e_s, v_s);
  } else {
    u16* ls = reinterpret_cast<u16*>(smem);
    float* wls = reinterpret_cast<float*>(smem + 10 * 28 * 64 * 2);
    const int b = blockIdx.x >> 3, h = blockIdx.x & 7, yt = y - 1;
    if (h < 2)      conv_head<3>(qkv, w3, b3, b, h, h,     yt, evbuf, ls, wls);
    else if (h < 5) conv_head<5>(qkv, w5, b5, b, h, h - 2, yt, evbuf, ls, wls);
    else            conv_head<7>(qkv, w7, b7, b, h, h - 5, yt, evbuf, ls, wls);
  }
}

// ---------------- combine: factor_att via MFMA + CRPE ----------------------
// Epilogue: two 128-row halves through f32 LDS (XOR-swizzled 16B chunks),
// then per-thread half-row ownership -> vectorized evbuf reads + attn stores.
__global__ __launch_bounds__(256)
void combine_kernel(const u16* __restrict__ qkv, const u16* __restrict__ kvT,
                    const u16* __restrict__ evbuf, u16* __restrict__ attn) {
  __shared__ __align__(16) float sa[128 * 64];   // 32 KB (one half)
  const int bh = blockIdx.x;
  const int b = bh >> 3, h = bh & 7;
  const int t = threadIdx.x;
  const int wave = t >> 6, lane = t & 63;
  const int quad = lane >> 4, l16 = lane & 15;
  const int tokbase = blockIdx.y * 256 + wave * 64;

  const u16* kvb = kvT + (size_t)bh * 4096;
  bf16x8 bfr[4][2];
#pragma unroll
  for (int j = 0; j < 4; ++j)
#pragma unroll
    for (int kk = 0; kk < 2; ++kk)
      bfr[j][kk] = *reinterpret_cast<const bf16x8*>(
          &kvb[(j * 16 + l16) * 64 + kk * 32 + quad * 8]);

  bf16x8 af[4][2];
#pragma unroll
  for (int i = 0; i < 4; ++i) {
    const int tok = min(tokbase + i * 16 + l16, NTOK - 1);
    const u16* qrow = qkv + (size_t)(b * NTOK + tok) * QKVN + h * CHD;
    af[i][0] = *reinterpret_cast<const bf16x8*>(&qrow[quad * 8]);
    af[i][1] = *reinterpret_cast<const bf16x8*>(&qrow[32 + quad * 8]);
  }

  f32x4 acc[4][4] = {};
#pragma unroll
  for (int kk = 0; kk < 2; ++kk)
#pragma unroll
    for (int i = 0; i < 4; ++i)
#pragma unroll
      for (int j = 0; j < 4; ++j)
        acc[i][j] = __builtin_amdgcn_mfma_f32_16x16x32_bf16(af[i][kk], bfr[j][kk], acc[i][j], 0, 0, 0);

  const float scale = 0.125f;
  const u16* evb = evbuf + (size_t)bh * IMGHW * 64;
#pragma unroll
  for (int half = 0; half < 2; ++half) {
    // phase 1: the two waves owning this half write scale*acc (f32, swizzled)
    if ((wave >> 1) == half) {
      const int rbase = (wave & 1) * 64;
#pragma unroll
      for (int i = 0; i < 4; ++i)
#pragma unroll
        for (int rr = 0; rr < 4; ++rr) {
          const int rl = rbase + i * 16 + quad * 4 + rr;
#pragma unroll
          for (int j = 0; j < 4; ++j) {
            const int dd = j * 16 + l16;
            sa[rl * 64 + (((dd >> 2) ^ (rl & 15)) * 4) + (dd & 3)] =
                scale * acc[i][j][rr];
          }
        }
    }
    __syncthreads();
    // phase 2: thread t owns half-row (rl = t>>1, d-half = t&1)
    {
      const int rl = t >> 1;
      const int tok = blockIdx.y * 256 + half * 128 + rl;
      if (tok < NTOK) {
        u16* orow = attn + (size_t)(b * NTOK + tok) * CDIM + h * CHD;
        const int cb = (t & 1) * 8;
#pragma unroll
        for (int c2 = 0; c2 < 4; ++c2) {
          const int ch0 = cb + c2 * 2;
          const f32x4 v0 = *reinterpret_cast<const f32x4*>(
              &sa[rl * 64 + ((ch0 ^ (rl & 15)) * 4)]);
          const f32x4 v1 = *reinterpret_cast<const f32x4*>(
              &sa[rl * 64 + (((ch0 + 1) ^ (rl & 15)) * 4)]);
          float o0 = v0[0], o1 = v0[1], o2 = v0[2], o3 = v0[3];
          float o4 = v1[0], o5 = v1[1], o6 = v1[2], o7 = v1[3];
          if (tok > 0) {
            const uint4 ev = *reinterpret_cast<const uint4*>(
                &evb[(size_t)(tok - 1) * 64 + ch0 * 4]);
            o0 += bflo(ev.x); o1 += bfhi(ev.x);
            o2 += bflo(ev.y); o3 += bfhi(ev.y);
            o4 += bflo(ev.z); o5 += bfhi(ev.z);
            o6 += bflo(ev.w); o7 += bfhi(ev.w);
          }
          uint4 ow;
          ow.x = pk2(o0, o1); ow.y = pk2(o2, o3);
          ow.z = pk2(o4, o5); ow.w = pk2(o6, o7);
          *reinterpret_cast<uint4*>(&orow[ch0 * 4]) = ow;
        }
      }
    }
    __syncthreads();   // guard sa reuse by next half
  }
}

// ---------------- launch ---------------------------------------------------
extern "C" void kernel_launch(void* const* d_in, const int* in_sizes, int n_in,
                              void* d_out, int out_size, void* d_ws, size_t ws_size,
                              hipStream_t stream) {
  const float* x      = (const float*)d_in[0];
  const float* qkv_w  = (const float*)d_in[1];
  const float* qkv_b  = (const float*)d_in[2];
  const float* proj_w = (const float*)d_in[3];
  const float* proj_b = (const float*)d_in[4];
  const float* w3 = (const float*)d_in[5];
  const float* b3 = (const float*)d_in[6];
  const float* w5 = (const float*)d_in[7];
  const float* b5 = (const float*)d_in[8];
  const float* w7 = (const float*)d_in[9];
  const float* b7 = (const float*)d_in[10];
  float* out = (float*)d_out;

  char* p = (char*)d_ws;
  u16* xb    = (u16*)p;   p += (size_t)MPAD * CDIM * 2;
  u16* wqb   = (u16*)p;   p += (size_t)QKVN * CDIM * 2;
  u16* wpb   = (u16*)p;   p += (size_t)CDIM * CDIM * 2;
  u16* qkvb  = (u16*)p;   p += (size_t)MPAD * QKVN * 2;
  u16* kvT   = (u16*)p;   p += (size_t)256 * 64 * 64 * 2;
  u16* attn  = (u16*)p;   p += (size_t)MPAD * CDIM * 2;
  // evbuf reuses xb (dead after gemm1): 256*784*64*2 = 25.7 MB <= 25.9 MB.
  u16* evbuf = xb;

  // 1. casts (single launch)
  {
    const int total = MROWS * CDIM / 4 + QKVN * CDIM / 4 + CDIM * CDIM / 4;
    casts_kernel<<<(total + 255) / 256, 256, 0, stream>>>(x, xb, qkv_w, wqb, proj_w, wpb);
  }
  // 2. qkv = x @ qkv_w^T + qkv_b  (bf16 out). nMt=99, nNt=12, XCD-banded grid.
  gemm_bt<1><<<13 * 8 * 12, 512, 0, stream>>>(xb, wqb, qkv_b, qkvb,
                                              MPAD, QKVN, CDIM, 99, 12);
  // 3. kv (full-token, pipelined, writes kvT) + depthwise convs + EV fuse
  kv_conv_kernel<<<dim3(256, 8), 256, 0, stream>>>(
      qkvb, kvT, w3, b3, w5, b5, w7, b7, evbuf);
  // 4. factor_att + CRPE -> attn (bf16)
  combine_kernel<<<dim3(256, 4), 256, 0, stream>>>(qkvb, kvT, evbuf, attn);
  // 5. out = attn @ proj_w^T + proj_b  (f32 out). nMt=99, nNt=4.
  gemm_bt<0><<<13 * 8 * 4, 512, 0, stream>>>(attn, wpb, proj_b, out,
                                             MROWS, CDIM, CDIM, 99, 4);
}

// Round 10
// 291.443 us; speedup vs baseline: 1.0343x; 1.0343x over previous
//
#include <hip/hip_runtime.h>
#include <cstdint>
#include <cstddef>

// CoaT factorized attention block, MI355X/gfx950.
// R15: (a) GEMM reverted to R8 exact (BK=32 dbuf + __syncthreads, 48 KB,
// 3 blk/CU) after R14's triple-buffer corner regressed 72->87 us — schedule
// search closed. (b) conv weight staging time-multiplexes the image-tile LDS
// region (weights -> LDS -> regs -> barrier -> image overwrites): smem
// 48.4 -> 35.8 KB => 4 blocks/CU for kv_conv (+33% waves on the stall-bound
// conv half). kv (R13 pipeline) frozen; combine (R9) frozen.

typedef unsigned short u16;

#define HEADS 8
#define CHD   64
#define CDIM  512
#define NTOK  785
#define BATCH 32
#define MROWS (BATCH * NTOK)   // 25120
#define MPAD  25344            // 99 * 256
#define QKVN  1536
#define IMGHW 784

typedef float  f32x4  __attribute__((ext_vector_type(4)));
typedef __bf16 bf16x8 __attribute__((ext_vector_type(8)));

__device__ __forceinline__ u16 f2bf(float f) {
  union { float f; uint32_t u; } x; x.f = f;
  uint32_t r = x.u + 0x7fffu + ((x.u >> 16) & 1u);  // RNE
  return (u16)(r >> 16);
}
__device__ __forceinline__ float bf2f(u16 u) {
  union { uint32_t u; float f; } x; x.u = ((uint32_t)u) << 16;
  return x.f;
}
__device__ __forceinline__ float bflo(uint32_t u) { return bf2f((u16)(u & 0xffffu)); }
__device__ __forceinline__ float bfhi(uint32_t u) { return bf2f((u16)(u >> 16)); }
// packed f32x2 -> bf16x2 (low = a, high = b)
__device__ __forceinline__ uint32_t pk2(float a, float b) {
#if __has_builtin(__builtin_amdgcn_cvt_pk_bf16_f32)
  auto v = __builtin_amdgcn_cvt_pk_bf16_f32(a, b);
  union { decltype(v) v2; uint32_t u; } cv; cv.v2 = v; return cv.u;
#else
  return (uint32_t)f2bf(a) | ((uint32_t)f2bf(b) << 16);
#endif
}

// ---------------- merged f32 -> bf16 casts (x, qkv_w, proj_w) --------------
__global__ __launch_bounds__(256)
void casts_kernel(const float* __restrict__ x, u16* __restrict__ xb,
                  const float* __restrict__ w1, u16* __restrict__ w1b,
                  const float* __restrict__ w2, u16* __restrict__ w2b) {
  const int N1 = MROWS * CDIM / 4, N2 = QKVN * CDIM / 4, N3 = CDIM * CDIM / 4;
  int i = blockIdx.x * 256 + threadIdx.x;
  const float* src; u16* dst;
  if (i < N1)           { src = x;  dst = xb;  }
  else if (i < N1 + N2) { i -= N1;  src = w1; dst = w1b; }
  else if (i < N1 + N2 + N3) { i -= N1 + N2; src = w2; dst = w2b; }
  else return;
  float4 v = reinterpret_cast<const float4*>(src)[i];
  uint2 o; o.x = pk2(v.x, v.y); o.y = pk2(v.z, v.w);
  reinterpret_cast<uint2*>(dst)[i] = o;
}

// ---------------- async global->LDS, 16B per lane --------------------------
__device__ __forceinline__ void gld_lds16(const u16* g, u16* l) {
  __builtin_amdgcn_global_load_lds((__attribute__((address_space(1))) void*)g,
                                   (__attribute__((address_space(3))) void*)l,
                                   16, 0, 0);
}

// ---------------- bf16 MFMA GEMM, C = A @ W^T + bias (R8, frozen) ----------
template <int OUTBF16>
__global__ __launch_bounds__(512)
void gemm_bt(const u16* __restrict__ A, const u16* __restrict__ W,
             const float* __restrict__ bias, void* __restrict__ Cout,
             int Mstore, int N, int K, int nMt, int nNt) {
  __shared__ __align__(16) u16 lsA[2][256 * 32];   // 32 KB
  __shared__ __align__(16) u16 lsB[2][128 * 32];   // 16 KB
  const int flat = blockIdx.x;
  const int xcd = flat & 7, idx = flat >> 3;
  const int nt = idx % nNt;
  const int mt = (idx / nNt) * 8 + xcd;
  if (mt >= nMt) return;
  const int tile_m = mt * 256, tile_n = nt * 128;

  const int tid  = threadIdx.x;
  const int wave = tid >> 6, lane = tid & 63;
  const int quad = lane >> 4, l16 = lane & 15;
  const int wm = (wave & 3) * 64, wn = (wave >> 2) * 64;

  const int srow = tid >> 2;                               // 0..127
  const int scol = ((tid & 3) ^ ((tid >> 3) & 3)) * 8;
  const int ldst = tid * 8;

  auto stage = [&](int kt, int buf) {
    const int kc = kt * 32 + scol;
#pragma unroll
    for (int s = 0; s < 2; ++s)
      gld_lds16(A + (size_t)(tile_m + s * 128 + srow) * K + kc,
                &lsA[buf][s * 4096 + ldst]);
    gld_lds16(W + (size_t)(tile_n + srow) * K + kc, &lsB[buf][ldst]);
  };

  f32x4 acc[4][4] = {};

  stage(0, 0);
  __syncthreads();

  const int KT = K >> 5;                 // 16 at both call sites
  const int pch = (quad ^ ((l16 >> 1) & 3)) * 8;   // physical chunk offset
#pragma unroll 2
  for (int t = 0; t < KT; ++t) {
    const int cur = t & 1;
    if (t + 1 < KT) stage(t + 1, cur ^ 1);
    bf16x8 af[4], bfr[4];
#pragma unroll
    for (int i = 0; i < 4; ++i) {
      af[i]  = *reinterpret_cast<const bf16x8*>(
          &lsA[cur][(wm + i * 16 + l16) * 32 + pch]);
      bfr[i] = *reinterpret_cast<const bf16x8*>(
          &lsB[cur][(wn + i * 16 + l16) * 32 + pch]);
    }
#pragma unroll
    for (int i = 0; i < 4; ++i)
#pragma unroll
      for (int j = 0; j < 4; ++j)
        acc[i][j] = __builtin_amdgcn_mfma_f32_16x16x32_bf16(
            af[i], bfr[j], acc[i][j], 0, 0, 0);
    __syncthreads();
  }

  // C/D layout: col = lane&15, row = quad*4 + reg
#pragma unroll
  for (int i = 0; i < 4; ++i) {
    const int mbase = tile_m + wm + i * 16 + quad * 4;
#pragma unroll
    for (int j = 0; j < 4; ++j) {
      const int n  = tile_n + wn + j * 16 + l16;
      const float bv = bias[n];
      const float v0 = acc[i][j][0] + bv, v1 = acc[i][j][1] + bv;
      const float v2 = acc[i][j][2] + bv, v3 = acc[i][j][3] + bv;
      if (OUTBF16) {
        u16* cp = reinterpret_cast<u16*>(Cout) + (size_t)mbase * N + n;
        const uint32_t p01 = pk2(v0, v1), p23 = pk2(v2, v3);
        if (mbase + 0 < Mstore) cp[0]            = (u16)p01;
        if (mbase + 1 < Mstore) cp[(size_t)N]    = (u16)(p01 >> 16);
        if (mbase + 2 < Mstore) cp[(size_t)N*2]  = (u16)p23;
        if (mbase + 3 < Mstore) cp[(size_t)N*3]  = (u16)(p23 >> 16);
      } else {
        float* cp = reinterpret_cast<float*>(Cout) + (size_t)mbase * N + n;
        if (mbase + 0 < Mstore) cp[0]           = v0;
        if (mbase + 1 < Mstore) cp[(size_t)N]   = v1;
        if (mbase + 2 < Mstore) cp[(size_t)N*2] = v2;
        if (mbase + 3 < Mstore) cp[(size_t)N*3] = v3;
      }
    }
  }
}

// ---------------- kv: full-token pass, pipelined, writes kvT directly ------
// Thread t owns c = (t&15)*4+{0..3}, d = (t>>4)*4+{0..3}; stages rows
// nl0 = t>>4 and nl0+16 of each 32-token chunk (4 uint2 loads -> regs).
// Double-buffered LDS, 1 barrier/chunk.
__device__ __forceinline__ void kv_part(
    const u16* __restrict__ qkv, u16* __restrict__ kvT, int bh,
    float* __restrict__ e_s, float* __restrict__ v_s) {
  const int b = bh >> 3, h = bh & 7;
  const int t = threadIdx.x;
  const int c4 = (t & 15) * 4;
  const int d4 = (t >> 4) * 4;
  const int nl0 = t >> 4;                 // 0..15
  const u16* kbase = qkv + (size_t)(b * NTOK) * QKVN + CDIM + h * CHD;
  const u16* vbase = kbase + CDIM;
  f32x4 acc[4] = {};              // acc[ci]: c = c4+ci, d = d4+{0..3}
  f32x4 sp4 = {0.f, 0.f, 0.f, 0.f};

  const int NCH = (NTOK + 31) / 32;       // 25
  uint2 rk0, rv0, rk1, rv1;
  auto issue = [&](int c) {
    const int na = c * 32 + nl0, nb = na + 16;
    if (na < NTOK) {
      rk0 = *reinterpret_cast<const uint2*>(&kbase[(size_t)na * QKVN + c4]);
      rv0 = *reinterpret_cast<const uint2*>(&vbase[(size_t)na * QKVN + c4]);
    }
    if (nb < NTOK) {
      rk1 = *reinterpret_cast<const uint2*>(&kbase[(size_t)nb * QKVN + c4]);
      rv1 = *reinterpret_cast<const uint2*>(&vbase[(size_t)nb * QKVN + c4]);
    }
  };

  issue(0);
  for (int c = 0; c < NCH; ++c) {
    float* eb = e_s + (c & 1) * 2048;
    float* vb = v_s + (c & 1) * 2048;
    const int na = c * 32 + nl0, nb = na + 16;
    f32x4 e4a = {}, v4a = {}, e4b = {}, v4b = {};
    if (na < NTOK) {
      e4a[0] = __expf(bflo(rk0.x)); e4a[1] = __expf(bfhi(rk0.x));
      e4a[2] = __expf(bflo(rk0.y)); e4a[3] = __expf(bfhi(rk0.y));
      v4a[0] = bflo(rv0.x); v4a[1] = bfhi(rv0.x);
      v4a[2] = bflo(rv0.y); v4a[3] = bfhi(rv0.y);
    }
    if (nb < NTOK) {
      e4b[0] = __expf(bflo(rk1.x)); e4b[1] = __expf(bfhi(rk1.x));
      e4b[2] = __expf(bflo(rk1.y)); e4b[3] = __expf(bfhi(rk1.y));
      v4b[0] = bflo(rv1.x); v4b[1] = bfhi(rv1.x);
      v4b[2] = bflo(rv1.y); v4b[3] = bfhi(rv1.y);
    }
    *reinterpret_cast<f32x4*>(&eb[nl0 * 64 + c4]) = e4a;
    *reinterpret_cast<f32x4*>(&vb[nl0 * 64 + c4]) = v4a;
    *reinterpret_cast<f32x4*>(&eb[(nl0 + 16) * 64 + c4]) = e4b;
    *reinterpret_cast<f32x4*>(&vb[(nl0 + 16) * 64 + c4]) = v4b;
    sp4 += e4a + e4b;
    if (c + 1 < NCH) issue(c + 1);    // next chunk's loads fly under compute
    __syncthreads();
    const int nc = min(32, NTOK - c * 32);
    for (int nl = 0; nl < nc; ++nl) {
      const f32x4 e4 = *reinterpret_cast<const f32x4*>(&eb[nl * 64 + c4]);
      const f32x4 v4 = *reinterpret_cast<const f32x4*>(&vb[nl * 64 + d4]);
      acc[0] += e4[0] * v4;
      acc[1] += e4[1] * v4;
      acc[2] += e4[2] * v4;
      acc[3] += e4[3] * v4;
    }
  }
  // S-reduction: S[c] = sum over the 16 threads with (t&15)==c>>2 of sp4[c&3]
  __syncthreads();
  *reinterpret_cast<f32x4*>(&e_s[t * 4]) = sp4;
  __syncthreads();
  if (t < 64) {
    float S = 0.f;
#pragma unroll
    for (int m = 0; m < 16; ++m)
      S += e_s[((t >> 2) + 16 * m) * 4 + (t & 3)];
    v_s[t] = S;
  }
  __syncthreads();
  const float S0 = v_s[c4], S1 = v_s[c4 + 1], S2 = v_s[c4 + 2], S3 = v_s[c4 + 3];
  // kvT[bh][d][c] = acc/S, bf16; per di a uint2 (4 c values) coalesced store
  u16* kb = kvT + (size_t)bh * 4096 + (size_t)d4 * 64 + c4;
#pragma unroll
  for (int di = 0; di < 4; ++di) {
    uint2 o;
    o.x = pk2(acc[0][di] / S0, acc[1][di] / S1);
    o.y = pk2(acc[2][di] / S2, acc[3][di] / S3);
    *reinterpret_cast<uint2*>(&kb[(size_t)di * 64]) = o;
  }
}

// ---------------- depthwise conv + EV fuse ---------------------------------
// Weights time-multiplex the image-tile LDS region: weights -> ls (f32) ->
// regs -> barrier -> image staging overwrites ls. Saves 12.5 KB of LDS,
// lifting kv_conv to 4 blocks/CU.
template <int KS>
__device__ __forceinline__ void conv_head(
    const u16* __restrict__ qkv, const float* __restrict__ wgt,
    const float* __restrict__ bias, int b, int head, int hh, int yt,
    u16* __restrict__ evbuf, u16* __restrict__ ls) {
  constexpr int PAD = KS / 2;
  constexpr int RIN = 4 + 2 * PAD;
  const int t = threadIdx.x;
  const int y0 = yt * 4;
  const int d = t & 63, yl = t >> 6;
  // phase A: weights through ls (coalesced global read, then per-d regs)
  float* wf = reinterpret_cast<float*>(ls);
  for (int i = t; i < 64 * KS * KS; i += 256)
    wf[i] = wgt[hh * 64 * KS * KS + i];
  __syncthreads();
  float wr[KS * KS];
#pragma unroll
  for (int i = 0; i < KS * KS; ++i) wr[i] = wf[d * KS * KS + i];
  const float bv = bias[hh * 64 + d];
  __syncthreads();   // all weight reads done before image overwrites ls
  // phase B: image staging (overwrites ls)
  const u16* vimg = qkv + (size_t)(b * NTOK + 1) * QKVN + 2 * CDIM + head * 64;
  const int c8 = (t & 7) * 8;
  for (int pi = t >> 3; pi < RIN * 28; pi += 32) {
    const int ry = pi / 28, rx = pi - ry * 28;
    const int yy = y0 - PAD + ry;
    uint4 val = {0, 0, 0, 0};
    if (yy >= 0 && yy < 28)
      val = *reinterpret_cast<const uint4*>(vimg + (size_t)(yy * 28 + rx) * QKVN + c8);
    *reinterpret_cast<uint4*>(ls + pi * 64 + c8) = val;
  }
  __syncthreads();
  float acc[28];
#pragma unroll
  for (int x = 0; x < 28; ++x) acc[x] = bv;
#pragma unroll
  for (int xx = 0; xx < 28; ++xx) {
    float col[KS];
#pragma unroll
    for (int r = 0; r < KS; ++r)
      col[r] = bf2f(ls[((yl + r) * 28 + xx) * 64 + d]);
#pragma unroll
    for (int j = 0; j < KS; ++j) {
      const int x = xx + PAD - j;
      if (x >= 0 && x < 28) {
#pragma unroll
        for (int r = 0; r < KS; ++r)
          acc[x] += col[r] * wr[r * KS + j];
      }
    }
  }
  const int p0 = (y0 + yl) * 28;
  const u16* qrow = qkv + (size_t)(b * NTOK + 1 + p0) * QKVN + head * 64 + d;
  u16* obase = evbuf + (((size_t)(b * 8 + head)) * IMGHW + p0) * 64 + d;
#pragma unroll
  for (int x = 0; x < 28; ++x) {
    const float ev = acc[x] * bf2f(qrow[(size_t)x * QKVN]);
    obase[(size_t)x * 64] = f2bf(ev);
  }
}

// ---------------- merged kv + conv (independent work, one launch) ----------
// grid (256, 8): y == 0 -> kv (full token range); y >= 1 -> conv yt = y-1.
// smem = 35840 B -> 4 blocks/CU.
__global__ __launch_bounds__(256)
void kv_conv_kernel(const u16* __restrict__ qkv, u16* __restrict__ kvT,
                    const float* __restrict__ w3, const float* __restrict__ b3,
                    const float* __restrict__ w5, const float* __restrict__ b5,
                    const float* __restrict__ w7, const float* __restrict__ b7,
                    u16* __restrict__ evbuf) {
  __shared__ __align__(16) char smem[10 * 28 * 64 * 2];   // 35 KB
  const int y = blockIdx.y;
  if (y == 0) {
    float* e_s = reinterpret_cast<float*>(smem);            // 2 x 8 KB
    float* v_s = e_s + 2 * 2048;                            // 2 x 8 KB
    kv_part(qkv, kvT, blockIdx.x, e_s, v_s);
  } else {
    u16* ls = reinterpret_cast<u16*>(smem);
    const int b = blockIdx.x >> 3, h = blockIdx.x & 7, yt = y - 1;
    if (h < 2)      conv_head<3>(qkv, w3, b3, b, h, h,     yt, evbuf, ls);
    else if (h < 5) conv_head<5>(qkv, w5, b5, b, h, h - 2, yt, evbuf, ls);
    else            conv_head<7>(qkv, w7, b7, b, h, h - 5, yt, evbuf, ls);
  }
}

// ---------------- combine: factor_att via MFMA + CRPE ----------------------
// Epilogue: two 128-row halves through f32 LDS (XOR-swizzled 16B chunks),
// then per-thread half-row ownership -> vectorized evbuf reads + attn stores.
__global__ __launch_bounds__(256)
void combine_kernel(const u16* __restrict__ qkv, const u16* __restrict__ kvT,
                    const u16* __restrict__ evbuf, u16* __restrict__ attn) {
  __shared__ __align__(16) float sa[128 * 64];   // 32 KB (one half)
  const int bh = blockIdx.x;
  const int b = bh >> 3, h = bh & 7;
  const int t = threadIdx.x;
  const int wave = t >> 6, lane = t & 63;
  const int quad = lane >> 4, l16 = lane & 15;
  const int tokbase = blockIdx.y * 256 + wave * 64;

  const u16* kvb = kvT + (size_t)bh * 4096;
  bf16x8 bfr[4][2];
#pragma unroll
  for (int j = 0; j < 4; ++j)
#pragma unroll
    for (int kk = 0; kk < 2; ++kk)
      bfr[j][kk] = *reinterpret_cast<const bf16x8*>(
          &kvb[(j * 16 + l16) * 64 + kk * 32 + quad * 8]);

  bf16x8 af[4][2];
#pragma unroll
  for (int i = 0; i < 4; ++i) {
    const int tok = min(tokbase + i * 16 + l16, NTOK - 1);
    const u16* qrow = qkv + (size_t)(b * NTOK + tok) * QKVN + h * CHD;
    af[i][0] = *reinterpret_cast<const bf16x8*>(&qrow[quad * 8]);
    af[i][1] = *reinterpret_cast<const bf16x8*>(&qrow[32 + quad * 8]);
  }

  f32x4 acc[4][4] = {};
#pragma unroll
  for (int kk = 0; kk < 2; ++kk)
#pragma unroll
    for (int i = 0; i < 4; ++i)
#pragma unroll
      for (int j = 0; j < 4; ++j)
        acc[i][j] = __builtin_amdgcn_mfma_f32_16x16x32_bf16(af[i][kk], bfr[j][kk], acc[i][j], 0, 0, 0);

  const float scale = 0.125f;
  const u16* evb = evbuf + (size_t)bh * IMGHW * 64;
#pragma unroll
  for (int half = 0; half < 2; ++half) {
    // phase 1: the two waves owning this half write scale*acc (f32, swizzled)
    if ((wave >> 1) == half) {
      const int rbase = (wave & 1) * 64;
#pragma unroll
      for (int i = 0; i < 4; ++i)
#pragma unroll
        for (int rr = 0; rr < 4; ++rr) {
          const int rl = rbase + i * 16 + quad * 4 + rr;
#pragma unroll
          for (int j = 0; j < 4; ++j) {
            const int dd = j * 16 + l16;
            sa[rl * 64 + (((dd >> 2) ^ (rl & 15)) * 4) + (dd & 3)] =
                scale * acc[i][j][rr];
          }
        }
    }
    __syncthreads();
    // phase 2: thread t owns half-row (rl = t>>1, d-half = t&1)
    {
      const int rl = t >> 1;
      const int tok = blockIdx.y * 256 + half * 128 + rl;
      if (tok < NTOK) {
        u16* orow = attn + (size_t)(b * NTOK + tok) * CDIM + h * CHD;
        const int cb = (t & 1) * 8;
#pragma unroll
        for (int c2 = 0; c2 < 4; ++c2) {
          const int ch0 = cb + c2 * 2;
          const f32x4 v0 = *reinterpret_cast<const f32x4*>(
              &sa[rl * 64 + ((ch0 ^ (rl & 15)) * 4)]);
          const f32x4 v1 = *reinterpret_cast<const f32x4*>(
              &sa[rl * 64 + (((ch0 + 1) ^ (rl & 15)) * 4)]);
          float o0 = v0[0], o1 = v0[1], o2 = v0[2], o3 = v0[3];
          float o4 = v1[0], o5 = v1[1], o6 = v1[2], o7 = v1[3];
          if (tok > 0) {
            const uint4 ev = *reinterpret_cast<const uint4*>(
                &evb[(size_t)(tok - 1) * 64 + ch0 * 4]);
            o0 += bflo(ev.x); o1 += bfhi(ev.x);
            o2 += bflo(ev.y); o3 += bfhi(ev.y);
            o4 += bflo(ev.z); o5 += bfhi(ev.z);
            o6 += bflo(ev.w); o7 += bfhi(ev.w);
          }
          uint4 ow;
          ow.x = pk2(o0, o1); ow.y = pk2(o2, o3);
          ow.z = pk2(o4, o5); ow.w = pk2(o6, o7);
          *reinterpret_cast<uint4*>(&orow[ch0 * 4]) = ow;
        }
      }
    }
    __syncthreads();   // guard sa reuse by next half
  }
}

// ---------------- launch ---------------------------------------------------
extern "C" void kernel_launch(void* const* d_in, const int* in_sizes, int n_in,
                              void* d_out, int out_size, void* d_ws, size_t ws_size,
                              hipStream_t stream) {
  const float* x      = (const float*)d_in[0];
  const float* qkv_w  = (const float*)d_in[1];
  const float* qkv_b  = (const float*)d_in[2];
  const float* proj_w = (const float*)d_in[3];
  const float* proj_b = (const float*)d_in[4];
  const float* w3 = (const float*)d_in[5];
  const float* b3 = (const float*)d_in[6];
  const float* w5 = (const float*)d_in[7];
  const float* b5 = (const float*)d_in[8];
  const float* w7 = (const float*)d_in[9];
  const float* b7 = (const float*)d_in[10];
  float* out = (float*)d_out;

  char* p = (char*)d_ws;
  u16* xb    = (u16*)p;   p += (size_t)MPAD * CDIM * 2;
  u16* wqb   = (u16*)p;   p += (size_t)QKVN * CDIM * 2;
  u16* wpb   = (u16*)p;   p += (size_t)CDIM * CDIM * 2;
  u16* qkvb  = (u16*)p;   p += (size_t)MPAD * QKVN * 2;
  u16* kvT   = (u16*)p;   p += (size_t)256 * 64 * 64 * 2;
  u16* attn  = (u16*)p;   p += (size_t)MPAD * CDIM * 2;
  // evbuf reuses xb (dead after gemm1): 256*784*64*2 = 25.7 MB <= 25.9 MB.
  u16* evbuf = xb;

  // 1. casts (single launch)
  {
    const int total = MROWS * CDIM / 4 + QKVN * CDIM / 4 + CDIM * CDIM / 4;
    casts_kernel<<<(total + 255) / 256, 256, 0, stream>>>(x, xb, qkv_w, wqb, proj_w, wpb);
  }
  // 2. qkv = x @ qkv_w^T + qkv_b  (bf16 out). nMt=99, nNt=12, XCD-banded grid.
  gemm_bt<1><<<13 * 8 * 12, 512, 0, stream>>>(xb, wqb, qkv_b, qkvb,
                                              MPAD, QKVN, CDIM, 99, 12);
  // 3. kv (full-token, pipelined, writes kvT) + depthwise convs + EV fuse
  kv_conv_kernel<<<dim3(256, 8), 256, 0, stream>>>(
      qkvb, kvT, w3, b3, w5, b5, w7, b7, evbuf);
  // 4. factor_att + CRPE -> attn (bf16)
  combine_kernel<<<dim3(256, 4), 256, 0, stream>>>(qkvb, kvT, evbuf, attn);
  // 5. out = attn @ proj_w^T + proj_b  (f32 out). nMt=99, nNt=4.
  gemm_bt<0><<<13 * 8 * 4, 512, 0, stream>>>(attn, wpb, proj_b, out,
                                             MROWS, CDIM, CDIM, 99, 4);
}